// Round 2
// baseline (251.899 us; speedup 1.0000x reference)
//
#include <hip/hip_runtime.h>
#include <hip/hip_bf16.h>

#define NTOT 2048
#define MTOT 2048
#define MSPLIT 16
#define MCHUNK 64

typedef short bf16x8 __attribute__((ext_vector_type(8)));
typedef float f32x4  __attribute__((ext_vector_type(4)));
typedef int   i32x4  __attribute__((ext_vector_type(4)));

// exp(x) = 2^(x*log2e); sigmoid(x) = 1/(1+2^(-x*log2e))
#define NL2E (-1.4426950408889634f)
// exp(-d2/5) = 2^(d2 * -log2e/5)
#define C1E  (-0.2885390081777927f)

__device__ __forceinline__ float fast_exp2(float x) {
#if __has_builtin(__builtin_amdgcn_exp2f)
  return __builtin_amdgcn_exp2f(x);
#else
  return __exp2f(x);
#endif
}
__device__ __forceinline__ float fast_rcp(float x) {
#if __has_builtin(__builtin_amdgcn_rcpf)
  return __builtin_amdgcn_rcpf(x);
#else
  return 1.0f / x;
#endif
}
__device__ __forceinline__ float fast_rsq(float x) {
#if __has_builtin(__builtin_amdgcn_rsqf)
  return __builtin_amdgcn_rsqf(x);
#else
  return rsqrtf(x);
#endif
}

// ---- dtype-polymorphic scalar load: f32 value from either storage ----
__device__ __forceinline__ float ldf(const __hip_bfloat16* p, int i) {
  return __bfloat162float(p[i]);
}
__device__ __forceinline__ float ldf(const float* p, int i) { return p[i]; }

// ---- bf16 raw-bits load (for MFMA B fragments) ----
__device__ __forceinline__ short to_bf16_rne(float x) {
  union { float f; unsigned u; } v; v.f = x;
  unsigned r = v.u + 0x7FFFu + ((v.u >> 16) & 1u);
  return (short)(r >> 16);
}
__device__ __forceinline__ short ldbf(const __hip_bfloat16* p, int i) {
  return ((const short*)p)[i];
}
__device__ __forceinline__ short ldbf(const float* p, int i) {
  return to_bf16_rne(p[i]);
}

// ---- output store ----
__device__ __forceinline__ void stf(__hip_bfloat16* p, int i, float v) {
  p[i] = __float2bfloat16(v);
}
__device__ __forceinline__ void stf(float* p, int i, float v) { p[i] = v; }

// pack two f32 -> two round-nearest bf16 in one u32 (lo in low half)
__device__ __forceinline__ unsigned pack_bf16_rn(float lo, float hi) {
  union { float f; unsigned u; } a, b;
  a.f = lo; b.f = hi;
  unsigned au = a.u + 0x8000u, bu = b.u + 0x8000u;
#if __has_builtin(__builtin_amdgcn_perm)
  return __builtin_amdgcn_perm(bu, au, 0x07060302u);
#else
  return (au >> 16) | (bu & 0xffff0000u);
#endif
}

// Deterministic dtype sniff: read first 128 halves of h_l as bf16.
// True-f32 data: low mantissa halves decode to huge/NaN bf16 values with
// probability ~1 (1 - 0.54^64). True-bf16 N(0,1) data: all |v| < ~6.
__device__ __forceinline__ int sniff_is_f32(const void* hl) {
  const unsigned short* p = (const unsigned short*)hl;
#pragma unroll 1
  for (int i = 0; i < 128; ++i) {
    unsigned u = ((unsigned)p[i]) << 16;
    float f = __builtin_bit_cast(float, u);
    if (!(fabsf(f) <= 1e3f)) return 1;  // catches >1e3, inf, NaN
  }
  return 0;
}

// ---------------------------------------------------------------------------
// Edge phase: per wave, 16 n-rows; loop over this block's m-range.
// For each m: edge feats -> 4->64 MLP+silu (VALU, directly in A-frag layout)
// -> 64->64 via 8x mfma_16x16x32_bf16 -> sigmoid -> accumulate num/den in regs.
// Grid: (NTOT/64) * MSPLIT blocks of 256 threads (4 waves x 16 n).
// ---------------------------------------------------------------------------
template <typename T, bool WANT_F32>
__global__ __launch_bounds__(256, 2)
void edge_kernel(const T* __restrict__ h_l,
                 const T* __restrict__ x_l,
                 const T* __restrict__ h_r,
                 const T* __restrict__ x_r,
                 const T* __restrict__ W1,
                 const T* __restrict__ b1,
                 const T* __restrict__ W2,
                 const T* __restrict__ b2,
                 float* __restrict__ num_g,
                 float* __restrict__ den_g) {
  if (sniff_is_f32(h_l) != (WANT_F32 ? 1 : 0)) return;  // uniform exit

  __shared__ float hr_s[MCHUNK][64];  // h_r chunk as f32 (16 KB)
  __shared__ float xr_s[MCHUNK][8];   // x_r(3), r_p(3), pad (2 KB)

  const int tid  = threadIdx.x;
  const int wave = tid >> 6;
  const int lane = tid & 63;
  const int l15  = lane & 15;
  const int quad = lane >> 4;

  const int nblk   = blockIdx.x / MSPLIT;
  const int msplit = blockIdx.x % MSPLIT;
  const int n0     = nblk * 64 + wave * 16;
  const int mPer   = MTOT / MSPLIT;  // 128
  const int mBase  = msplit * mPer;

  // per-lane A-row n
  const int nA = n0 + l15;
  const float xl0 = ldf(x_l, nA * 3 + 0);
  const float xl1 = ldf(x_l, nA * 3 + 1);
  const float xl2 = ldf(x_l, nA * 3 + 2);
  const float lp0 = ldf(h_l, nA * 64 + 61);
  const float lp1 = ldf(h_l, nA * 64 + 62);
  const float lp2 = ldf(h_l, nA * 64 + 63);

  // layer-1 weights for this lane's 16 h1 columns (h1 = quad*8+j and 32+quad*8+j)
  float w1d[16], w1h[16], w1y[16], b1p[16];
#pragma unroll
  for (int j = 0; j < 8; ++j) {
    const int ha = quad * 8 + j, hb = 32 + quad * 8 + j;
    w1d[j] = ldf(W1, 0 * 64 + ha);   w1d[8 + j] = ldf(W1, 0 * 64 + hb);
    w1h[j] = ldf(W1, 1 * 64 + ha);   w1h[8 + j] = ldf(W1, 1 * 64 + hb);
    w1y[j] = ldf(W1, 2 * 64 + ha);   w1y[8 + j] = ldf(W1, 2 * 64 + hb);
    // edge_raw[3] == 1 -> fold W1 row 3 into bias
    b1p[j]     = ldf(b1, ha) + ldf(W1, 3 * 64 + ha);
    b1p[8 + j] = ldf(b1, hb) + ldf(W1, 3 * 64 + hb);
  }

  // W2 B-frags: B[k = half*32 + quad*8 + j][col = c*16 + l15]
  bf16x8 Bfrag[4][2];
#pragma unroll
  for (int c = 0; c < 4; ++c) {
#pragma unroll
    for (int h = 0; h < 2; ++h) {
      bf16x8 f;
#pragma unroll
      for (int j = 0; j < 8; ++j) {
        const int k = h * 32 + quad * 8 + j;
        f[j] = ldbf(W2, k * 64 + c * 16 + l15);
      }
      Bfrag[c][h] = f;
    }
  }

  // b2 folded into sigmoid exp-arg: arg = e*NL2E + NL2E*b2[h2]
  float b2c[4];
#pragma unroll
  for (int c = 0; c < 4; ++c) b2c[c] = NL2E * ldf(b2, c * 16 + l15);

  const f32x4 zero4 = {0.f, 0.f, 0.f, 0.f};
  float numr[4][4], denr[4][4];
#pragma unroll
  for (int c = 0; c < 4; ++c)
#pragma unroll
    for (int r = 0; r < 4; ++r) { numr[c][r] = 0.f; denr[c][r] = 0.f; }

  for (int mc = 0; mc < mPer; mc += MCHUNK) {
    __syncthreads();
    // stage h_r chunk (f32) + x_r/r_p chunk
    for (int idx = tid; idx < MCHUNK * 64; idx += 256) {
      const int mm = idx >> 6, hh = idx & 63;
      hr_s[mm][hh] = ldf(h_r, (mBase + mc + mm) * 64 + hh);
    }
    for (int idx = tid; idx < MCHUNK * 8; idx += 256) {
      const int mm = idx >> 3, k = idx & 7;
      float v = 0.f;
      const int m = mBase + mc + mm;
      if (k < 3)      v = ldf(x_r, m * 3 + k);
      else if (k < 6) v = ldf(h_r, m * 64 + 61 + (k - 3));
      xr_s[mm][k] = v;
    }
    __syncthreads();

#pragma unroll 1
    for (int ms = 0; ms < MCHUNK; ++ms) {
      // broadcast per-m values
      const float xr0 = xr_s[ms][0], xr1 = xr_s[ms][1], xr2 = xr_s[ms][2];
      const float rp0 = xr_s[ms][3], rp1 = xr_s[ms][4], rp2 = xr_s[ms][5];
      const float dx = xl0 - xr0, dy = xl1 - xr1, dz = xl2 - xr2;
      const float d2 = fmaf(dz, dz, fmaf(dy, dy, dx * dx));
      const float dist = fast_exp2(d2 * C1E);          // exp(-d2/5)
      const float hb = fmaf(lp1, rp0, lp0 * rp1);
      const float hy = lp2 * rp2;

      // layer 1 + silu, directly in A-frag element order
      float s[16];
#pragma unroll
      for (int j = 0; j < 16; ++j) {
        const float t = fmaf(dist, w1d[j], fmaf(hb, w1h[j], fmaf(hy, w1y[j], b1p[j])));
        s[j] = t * fast_rcp(1.0f + fast_exp2(t * NL2E));  // silu
      }
      i32x4 p0, p1;
      p0.x = pack_bf16_rn(s[0], s[1]);   p0.y = pack_bf16_rn(s[2], s[3]);
      p0.z = pack_bf16_rn(s[4], s[5]);   p0.w = pack_bf16_rn(s[6], s[7]);
      p1.x = pack_bf16_rn(s[8], s[9]);   p1.y = pack_bf16_rn(s[10], s[11]);
      p1.z = pack_bf16_rn(s[12], s[13]); p1.w = pack_bf16_rn(s[14], s[15]);
      const bf16x8 A0 = __builtin_bit_cast(bf16x8, p0);
      const bf16x8 A1 = __builtin_bit_cast(bf16x8, p1);

      f32x4 acc[4];
#pragma unroll
      for (int c = 0; c < 4; ++c) {
        acc[c] = __builtin_amdgcn_mfma_f32_16x16x32_bf16(A0, Bfrag[c][0], zero4, 0, 0, 0);
        acc[c] = __builtin_amdgcn_mfma_f32_16x16x32_bf16(A1, Bfrag[c][1], acc[c], 0, 0, 0);
      }

      // sigmoid + accumulate: lane holds e[n = n0+quad*4+r][h2 = c*16+l15]
#pragma unroll
      for (int c = 0; c < 4; ++c) {
        const float hrv = hr_s[ms][c * 16 + l15];
#pragma unroll
        for (int r = 0; r < 4; ++r) {
          const float w = fast_rcp(1.0f + fast_exp2(fmaf(acc[c][r], NL2E, b2c[c])));
          numr[c][r] = fmaf(w, hrv, numr[c][r]);
          denr[c][r] += w;
        }
      }
    }
  }

#pragma unroll
  for (int c = 0; c < 4; ++c)
#pragma unroll
    for (int r = 0; r < 4; ++r) {
      const int n = n0 + quad * 4 + r;
      const int h2 = c * 16 + l15;
      atomicAdd(&num_g[n * 64 + h2], numr[c][r]);
      atomicAdd(&den_g[n * 64 + h2], denr[c][r]);
    }
}

// ---------------------------------------------------------------------------
// Node phase: one wave per row. h_agg = num/(den+1e-6); z = cat(h_l,h_agg)@Wn1
// + bn1 -> LN -> silu -> @Wn2 + bn2; out = h_l + z.
// ---------------------------------------------------------------------------
template <typename T, bool WANT_F32>
__global__ __launch_bounds__(256)
void node_kernel(const T* __restrict__ h_l,
                 const float* __restrict__ num_g,
                 const float* __restrict__ den_g,
                 const T* __restrict__ Wn1,
                 const T* __restrict__ bn1,
                 const T* __restrict__ ln_g,
                 const T* __restrict__ ln_b,
                 const T* __restrict__ Wn2,
                 const T* __restrict__ bn2,
                 T* __restrict__ out) {
  if (sniff_is_f32(h_l) != (WANT_F32 ? 1 : 0)) return;  // uniform exit

  __shared__ float Wn1_s[128 * 64];
  __shared__ float Wn2_s[64 * 64];
  __shared__ float xbuf[4][128];
  __shared__ float zbuf[4][64];

  const int tid = threadIdx.x;
  for (int i = tid; i < 128 * 64; i += 256) Wn1_s[i] = ldf(Wn1, i);
  for (int i = tid; i < 64 * 64; i += 256) Wn2_s[i] = ldf(Wn2, i);

  const int wave = tid >> 6, lane = tid & 63;
  const int row = blockIdx.x * 4 + wave;

  const float hl = ldf(h_l, row * 64 + lane);
  const float dn = den_g[row * 64 + lane] + 1e-6f;
  const float hagg = num_g[row * 64 + lane] * fast_rcp(dn);
  xbuf[wave][lane] = hl;
  xbuf[wave][64 + lane] = hagg;
  __syncthreads();

  float t = ldf(bn1, lane);
#pragma unroll 8
  for (int k = 0; k < 128; ++k) t = fmaf(xbuf[wave][k], Wn1_s[k * 64 + lane], t);

  float s1 = t, s2 = t * t;
#pragma unroll
  for (int off = 32; off; off >>= 1) {
    s1 += __shfl_xor(s1, off);
    s2 += __shfl_xor(s2, off);
  }
  const float mu = s1 * 0.015625f;
  const float var = fmaf(s2, 0.015625f, -mu * mu);
  const float rs = fast_rsq(var + 1e-5f);
  const float zn = fmaf((t - mu) * rs, ldf(ln_g, lane), ldf(ln_b, lane));
  const float sz = zn * fast_rcp(1.0f + fast_exp2(zn * NL2E));  // silu
  zbuf[wave][lane] = sz;
  __syncthreads();

  float o = ldf(bn2, lane);
#pragma unroll 8
  for (int k = 0; k < 64; ++k) o = fmaf(zbuf[wave][k], Wn2_s[k * 64 + lane], o);

  stf(out, row * 64 + lane, hl + o);
}

extern "C" void kernel_launch(void* const* d_in, const int* in_sizes, int n_in,
                              void* d_out, int out_size, void* d_ws, size_t ws_size,
                              hipStream_t stream) {
  float* num_g = (float*)d_ws;
  float* den_g = num_g + (size_t)NTOT * 64;

  hipMemsetAsync(d_ws, 0, (size_t)NTOT * 64 * 2 * sizeof(float), stream);

  const dim3 egrid((NTOT / 64) * MSPLIT), eblk(256);
  const dim3 ngrid(NTOT / 4), nblk2(256);

  // bf16 interpretation
  {
    typedef __hip_bfloat16 T;
    edge_kernel<T, false><<<egrid, eblk, 0, stream>>>(
        (const T*)d_in[0], (const T*)d_in[1], (const T*)d_in[2], (const T*)d_in[3],
        (const T*)d_in[4], (const T*)d_in[5], (const T*)d_in[6], (const T*)d_in[7],
        num_g, den_g);
    node_kernel<T, false><<<ngrid, nblk2, 0, stream>>>(
        (const T*)d_in[0], num_g, den_g,
        (const T*)d_in[8], (const T*)d_in[9], (const T*)d_in[10], (const T*)d_in[11],
        (const T*)d_in[12], (const T*)d_in[13], (T*)d_out);
  }
  // f32 interpretation
  {
    typedef float T;
    edge_kernel<T, true><<<egrid, eblk, 0, stream>>>(
        (const T*)d_in[0], (const T*)d_in[1], (const T*)d_in[2], (const T*)d_in[3],
        (const T*)d_in[4], (const T*)d_in[5], (const T*)d_in[6], (const T*)d_in[7],
        num_g, den_g);
    node_kernel<T, true><<<ngrid, nblk2, 0, stream>>>(
        (const T*)d_in[0], num_g, den_g,
        (const T*)d_in[8], (const T*)d_in[9], (const T*)d_in[10], (const T*)d_in[11],
        (const T*)d_in[12], (const T*)d_in[13], (T*)d_out);
  }
}